// Round 3
// baseline (199.235 us; speedup 1.0000x reference)
//
#include <hip/hip_runtime.h>
#include <cstdint>
#include <math.h>

// SoftmaxGaussian: out_mean/out_var over 10000 MC softmax samples with
// JAX threefry2x32-exact random draw (key(42), shape (512,16,10000)).
//
// Layout facts:
//   N = 512*16*10000 = 81,920,000 ; half = 40,960,000 = 256*16*10000
//   flat j=(b*16+k)*10000+s ; threefry block i in [0,half):
//     counters (i, i+half), key (0,42) -> (z[j=i], z[j=i+half])
//   => block i yields samples for (b,k,s) AND (b+256,k,s). One b per block-row.
//
// R3: R2's launch_bounds(512,4) made the compiler cap VGPRs at 64 -> massive
// scratch spills (254 MB/dispatch @ 1.2 TB/s). Revert to (512,2) (R1-proven
// 104 VGPR, no spill; still allows 2 blocks/CU with the 1024-block grid).
// Keep SPLIT=4 grid + Giles erfinv. New: log2-domain softmax (exp2f = bare
// v_exp_f32) and __log2f-based erfinv with ln2 folded into the poly argument.

#define NSAMP 10000
#define HALF_N 40960000u
#define THREADS 512
#define SPLIT 4
#define CHUNK (NSAMP / SPLIT)  // 2500
#define WS_NEEDED (256 * SPLIT * 64 * sizeof(float))  // 262144 B

#define LOG2E 1.44269504088896340736f
#define LN2 0.69314718055994530942f
#define SQRT_LN2 0.83255461115769775635f

__device__ __forceinline__ uint32_t rotl32(uint32_t x, int r) {
    return (x << r) | (x >> (32 - r));  // v_alignbit_b32
}

// JAX threefry2x32, key = (0, 42)
__device__ __forceinline__ void threefry2x32_k42(uint32_t x0, uint32_t x1,
                                                 uint32_t& o0, uint32_t& o1) {
    const uint32_t ks0 = 0u;
    const uint32_t ks1 = 42u;
    const uint32_t ks2 = 0x1BD11BDAu ^ 0u ^ 42u;
    x0 += ks0;
    x1 += ks1;
#define TF_R(r) { x0 += x1; x1 = rotl32(x1, r); x1 ^= x0; }
    TF_R(13) TF_R(15) TF_R(26) TF_R(6)   x0 += ks1; x1 += ks2 + 1u;
    TF_R(17) TF_R(29) TF_R(16) TF_R(24)  x0 += ks2; x1 += ks0 + 2u;
    TF_R(13) TF_R(15) TF_R(26) TF_R(6)   x0 += ks0; x1 += ks1 + 3u;
    TF_R(17) TF_R(29) TF_R(16) TF_R(24)  x0 += ks1; x1 += ks2 + 4u;
    TF_R(13) TF_R(15) TF_R(26) TF_R(6)   x0 += ks2; x1 += ks0 + 5u;
#undef TF_R
    o0 = x0;
    o1 = x1;
}

// JAX uniform(lo=nextafter(-1,0), hi=1) from raw bits (float32 path)
__device__ __forceinline__ float u_from_bits(uint32_t bits) {
    float f = __uint_as_float((bits >> 9) | 0x3F800000u) - 1.0f; // [0,1)
    const float lo = -0.99999994f;                               // nextafterf(-1,0)
    return fmaxf(lo, fmaf(f, 1.0f - lo, lo));
}

// XLA's ErfInv f32 (Giles 2012), branchless; log2-domain input:
//   w2 = -log2(1-x^2), w = ln2*w2. Main path w<5 <=> w2 < 5/ln2.
__device__ __forceinline__ float erfinv_giles(float x) {
    float w2 = -__log2f(fmaf(-x, x, 1.0f));      // v_log_f32
    // main path (w < 5): wm = w - 2.5 = ln2*w2 - 2.5
    float wm = fmaf(LN2, w2, -2.5f);
    float p1 = 2.81022636e-08f;
    p1 = fmaf(p1, wm, 3.43273939e-07f);
    p1 = fmaf(p1, wm, -3.5233877e-06f);
    p1 = fmaf(p1, wm, -4.39150654e-06f);
    p1 = fmaf(p1, wm, 0.00021858087f);
    p1 = fmaf(p1, wm, -0.00125372503f);
    p1 = fmaf(p1, wm, -0.00417768164f);
    p1 = fmaf(p1, wm, 0.246640727f);
    p1 = fmaf(p1, wm, 1.50140941f);
    // tail path (w >= 5): wt = sqrt(w) - 3 = sqrt(ln2)*sqrt(w2) - 3
    float wt = fmaf(SQRT_LN2, sqrtf(w2), -3.0f);
    float p2 = -0.000200214257f;
    p2 = fmaf(p2, wt, 0.000100950558f);
    p2 = fmaf(p2, wt, 0.00134934322f);
    p2 = fmaf(p2, wt, -0.00367342844f);
    p2 = fmaf(p2, wt, 0.00573950773f);
    p2 = fmaf(p2, wt, -0.0076224613f);
    p2 = fmaf(p2, wt, 0.00943887047f);
    p2 = fmaf(p2, wt, 1.00167406f);
    p2 = fmaf(p2, wt, 2.83297682f);
    float p = (w2 < 7.2134752044448170f) ? p1 : p2;  // 5/ln2
    return p * x;
}

__device__ __forceinline__ float wave_sum(float v) {
    v += __shfl_down(v, 32);
    v += __shfl_down(v, 16);
    v += __shfl_down(v, 8);
    v += __shfl_down(v, 4);
    v += __shfl_down(v, 2);
    v += __shfl_down(v, 1);
    return v;
}

// Accumulate samples [s_begin, s_end) for batch-row b (and b+256) and leave
// the block-reduced 64 partials {sum0,sq0,sum1,sq1} per k in s_fin[64].
// s_mu / s_sv hold log2e-scaled mean and sqrt(2*var): softmax done in log2
// domain (exp2f = single v_exp_f32), invariant under the common scale.
__device__ __forceinline__ void sg_accumulate(const float* __restrict__ mean,
                                              const float* __restrict__ var,
                                              int b, int s_begin, int s_end,
                                              float* s_mu, float* s_sv,
                                              float* s_red, float* s_fin) {
    const int tid = threadIdx.x;

    if (tid < 32) {
        int h = tid >> 4, k = tid & 15;
        int bg = b + 256 * h;
        s_mu[tid] = LOG2E * mean[bg * 16 + k];
        s_sv[tid] = (LOG2E * 1.41421356237309515f) * sqrtf(var[bg * 16 + k]);
    }
    __syncthreads();

    float accs0[16], accq0[16], accs1[16], accq1[16];
#pragma unroll
    for (int k = 0; k < 16; k++) { accs0[k] = 0.f; accq0[k] = 0.f; accs1[k] = 0.f; accq1[k] = 0.f; }

    const uint32_t base_bk = (uint32_t)(b * 16) * 10000u;

    for (int s = s_begin + tid; s < s_end; s += THREADS) {
        float x0v[16], x1v[16];
#pragma unroll
        for (int k = 0; k < 16; k++) {
            uint32_t i = base_bk + (uint32_t)(k * 10000) + (uint32_t)s;
            uint32_t o0, o1;
            threefry2x32_k42(i, i + HALF_N, o0, o1);
            float z0 = erfinv_giles(u_from_bits(o0));
            float z1 = erfinv_giles(u_from_bits(o1));
            x0v[k] = fmaf(z0, s_sv[k],      s_mu[k]);       // batch b (log2 dom)
            x1v[k] = fmaf(z1, s_sv[16 + k], s_mu[16 + k]);  // batch b+256
        }
        float m0 = x0v[0], m1 = x1v[0];
#pragma unroll
        for (int k = 1; k < 16; k++) { m0 = fmaxf(m0, x0v[k]); m1 = fmaxf(m1, x1v[k]); }
        float sum0 = 0.f, sum1 = 0.f;
#pragma unroll
        for (int k = 0; k < 16; k++) {
            x0v[k] = exp2f(x0v[k] - m0); sum0 += x0v[k];
            x1v[k] = exp2f(x1v[k] - m1); sum1 += x1v[k];
        }
        float inv0 = 1.0f / sum0, inv1 = 1.0f / sum1;
#pragma unroll
        for (int k = 0; k < 16; k++) {
            float p0 = x0v[k] * inv0;
            float p1 = x1v[k] * inv1;
            accs0[k] += p0; accq0[k] = fmaf(p0, p0, accq0[k]);
            accs1[k] += p1; accq1[k] = fmaf(p1, p1, accq1[k]);
        }
    }

    const int lane = tid & 63, wave = tid >> 6;
#pragma unroll
    for (int k = 0; k < 16; k++) {
        float v0 = wave_sum(accs0[k]);
        float q0 = wave_sum(accq0[k]);
        float v1 = wave_sum(accs1[k]);
        float q1 = wave_sum(accq1[k]);
        if (lane == 0) {
            s_red[wave * 64 + k * 4 + 0] = v0;
            s_red[wave * 64 + k * 4 + 1] = q0;
            s_red[wave * 64 + k * 4 + 2] = v1;
            s_red[wave * 64 + k * 4 + 3] = q1;
        }
    }
    __syncthreads();

    if (tid < 64) {
        float t = 0.f;
#pragma unroll
        for (int w = 0; w < 8; w++) t += s_red[w * 64 + tid];
        s_fin[tid] = t;
    }
    __syncthreads();
}

// ---- split path: 256*SPLIT blocks write partials to ws ----
__global__ __launch_bounds__(THREADS, 2)
void sg_partial(const float* __restrict__ mean, const float* __restrict__ var,
                float* __restrict__ ws) {
    __shared__ float s_mu[32], s_sv[32], s_red[8 * 64], s_fin[64];
    const int b = blockIdx.x >> 2;       // 0..255
    const int chunk = blockIdx.x & 3;    // 0..SPLIT-1
    sg_accumulate(mean, var, b, chunk * CHUNK, (chunk + 1) * CHUNK,
                  s_mu, s_sv, s_red, s_fin);
    if (threadIdx.x < 64) ws[blockIdx.x * 64 + threadIdx.x] = s_fin[threadIdx.x];
}

__global__ __launch_bounds__(256)
void sg_finalize(const float* __restrict__ ws, float* __restrict__ out) {
    int t = blockIdx.x * blockDim.x + threadIdx.x;  // 0..8191
    if (t >= 8192) return;
    int k = t & 15, h = (t >> 4) & 1, b = t >> 5;
    float sum = 0.f, sq = 0.f;
#pragma unroll
    for (int c = 0; c < SPLIT; c++) {
        const float* p = ws + ((b * SPLIT + c) * 64 + k * 4 + 2 * h);
        sum += p[0];
        sq += p[1];
    }
    float mu = sum * (1.0f / 10000.0f);
    float vr = (sq - sum * mu) * (1.0f / 9999.0f);  // unbiased
    int bg = b + 256 * h;
    out[bg * 16 + k] = mu;
    out[8192 + bg * 16 + k] = vr;
}

// ---- fallback (ws too small): single kernel, one block per b ----
__global__ __launch_bounds__(THREADS, 2)
void sg_kernel(const float* __restrict__ mean, const float* __restrict__ var,
               float* __restrict__ out) {
    __shared__ float s_mu[32], s_sv[32], s_red[8 * 64], s_fin[64];
    const int b = blockIdx.x;
    sg_accumulate(mean, var, b, 0, NSAMP, s_mu, s_sv, s_red, s_fin);
    const int tid = threadIdx.x;
    if (tid < 32) {
        int h = tid >> 4, k = tid & 15;
        float sum = s_fin[k * 4 + 2 * h + 0];
        float sq  = s_fin[k * 4 + 2 * h + 1];
        float mu = sum * (1.0f / 10000.0f);
        float vr = (sq - sum * mu) * (1.0f / 9999.0f);
        int bg = b + 256 * h;
        out[bg * 16 + k] = mu;
        out[8192 + bg * 16 + k] = vr;
    }
}

extern "C" void kernel_launch(void* const* d_in, const int* in_sizes, int n_in,
                              void* d_out, int out_size, void* d_ws, size_t ws_size,
                              hipStream_t stream) {
    const float* mean = (const float*)d_in[0];
    const float* var  = (const float*)d_in[1];
    float* out = (float*)d_out;
    if (ws_size >= WS_NEEDED) {
        float* ws = (float*)d_ws;
        sg_partial<<<256 * SPLIT, THREADS, 0, stream>>>(mean, var, ws);
        sg_finalize<<<32, 256, 0, stream>>>(ws, out);
    } else {
        sg_kernel<<<256, THREADS, 0, stream>>>(mean, var, out);
    }
}

// Round 4
// 185.344 us; speedup vs baseline: 1.0749x; 1.0749x over previous
//
#include <hip/hip_runtime.h>
#include <cstdint>
#include <math.h>

// SoftmaxGaussian: out_mean/out_var over 10000 MC softmax samples with
// JAX threefry2x32-exact random draw (key(42), shape (512,16,10000)).
//
// Layout facts:
//   N = 512*16*10000 = 81,920,000 ; half = 40,960,000 = 256*16*10000
//   flat j=(b*16+k)*10000+s ; threefry block i in [0,half):
//     counters (i, i+half), key (0,42) -> (z[j=i], z[j=i+half])
//   => block i yields samples for (b,k,s) AND (b+256,k,s).
//
// R4: VALU-issue-bound (R3: 88% VALUBusy, occupancy-insensitive). Cut issue
// slots: (1) packed-FP32 (v_pk_fma_f32 etc.) by pairing adjacent k's as
// float2 ext-vectors — halves the ~1100 scalar f32 ops/iter; (2) drop
// softmax max-subtract (log2-domain |x|<=~15: exp2 cannot overflow);
// (3) drop redundant fmax in uniform map; (4) raw v_rcp/v_exp/v_log/v_sqrt
// via __builtin_amdgcn_* (no exact-division expansion).

typedef float f32x2 __attribute__((ext_vector_type(2)));

#define NSAMP 10000
#define HALF_N 40960000u
#define THREADS 512
#define SPLIT 4
#define CHUNK (NSAMP / SPLIT)  // 2500
#define WS_NEEDED (256 * SPLIT * 64 * sizeof(float))  // 262144 B

#define LOG2E 1.44269504088896340736f
#define NLN2 -0.69314718055994530942f
#define SQRT_LN2 0.83255461115769775635f

__device__ __forceinline__ uint32_t rotl32(uint32_t x, int r) {
    return (x << r) | (x >> (32 - r));  // v_alignbit_b32
}

// JAX threefry2x32, key = (0, 42)
__device__ __forceinline__ void tf2x32(uint32_t x0, uint32_t x1,
                                       uint32_t& o0, uint32_t& o1) {
    const uint32_t ks1 = 42u;
    const uint32_t ks2 = 0x1BD11BDAu ^ 42u;
    x1 += ks1;
#define TF_R(r) { x0 += x1; x1 = rotl32(x1, r); x1 ^= x0; }
    TF_R(13) TF_R(15) TF_R(26) TF_R(6)   x0 += ks1; x1 += ks2 + 1u;
    TF_R(17) TF_R(29) TF_R(16) TF_R(24)  x0 += ks2; x1 += 2u;
    TF_R(13) TF_R(15) TF_R(26) TF_R(6)                x1 += ks1 + 3u;
    TF_R(17) TF_R(29) TF_R(16) TF_R(24)  x0 += ks1; x1 += ks2 + 4u;
    TF_R(13) TF_R(15) TF_R(26) TF_R(6)   x0 += ks2; x1 += 5u;
#undef TF_R
    o0 = x0;
    o1 = x1;
}

// JAX uniform(lo=nextafter(-1,0), hi=1), packed pair.
// u = f*2 + lo (exact match to JAX's mul-add: f*2 is exact, one rounding).
// fmax(lo,.) is redundant: f=0 -> exactly lo; f>0 -> strictly > lo under RN.
__device__ __forceinline__ f32x2 u2_from_bits(uint32_t ba, uint32_t bb) {
    f32x2 f;
    f.x = __uint_as_float((ba >> 9) | 0x3F800000u);
    f.y = __uint_as_float((bb >> 9) | 0x3F800000u);
    f = f - (f32x2){1.0f, 1.0f};  // exact (Sterbenz)
    return __builtin_elementwise_fma(f, (f32x2){2.0f, 2.0f},
                                     (f32x2){-0.99999994f, -0.99999994f});
}

// XLA's ErfInv f32 (Giles 2012), branchless both-path, packed pair.
// l = log2(1-x^2) <= 0 ; w = -ln2*l ; main path w<5 <=> l > -5/ln2.
__device__ __forceinline__ f32x2 erfinv2(f32x2 x) {
    f32x2 t = __builtin_elementwise_fma(-x, x, (f32x2){1.0f, 1.0f});
    f32x2 l;
    l.x = __builtin_amdgcn_logf(t.x);
    l.y = __builtin_amdgcn_logf(t.y);
    f32x2 wm = __builtin_elementwise_fma((f32x2){NLN2, NLN2}, l,
                                         (f32x2){-2.5f, -2.5f});
#define P9(P, W, C) P = __builtin_elementwise_fma(P, W, (f32x2){C, C});
    f32x2 p1 = {2.81022636e-08f, 2.81022636e-08f};
    P9(p1, wm, 3.43273939e-07f)
    P9(p1, wm, -3.5233877e-06f)
    P9(p1, wm, -4.39150654e-06f)
    P9(p1, wm, 0.00021858087f)
    P9(p1, wm, -0.00125372503f)
    P9(p1, wm, -0.00417768164f)
    P9(p1, wm, 0.246640727f)
    P9(p1, wm, 1.50140941f)
    f32x2 sq;
    sq.x = __builtin_amdgcn_sqrtf(-l.x);   // sqrt(w2), neg folds to src-mod
    sq.y = __builtin_amdgcn_sqrtf(-l.y);
    f32x2 wt = __builtin_elementwise_fma((f32x2){SQRT_LN2, SQRT_LN2}, sq,
                                         (f32x2){-3.0f, -3.0f});
    f32x2 p2 = {-0.000200214257f, -0.000200214257f};
    P9(p2, wt, 0.000100950558f)
    P9(p2, wt, 0.00134934322f)
    P9(p2, wt, -0.00367342844f)
    P9(p2, wt, 0.00573950773f)
    P9(p2, wt, -0.0076224613f)
    P9(p2, wt, 0.00943887047f)
    P9(p2, wt, 1.00167406f)
    P9(p2, wt, 2.83297682f)
#undef P9
    f32x2 p;
    p.x = (l.x > -7.2134752f) ? p1.x : p2.x;  // -5/ln2
    p.y = (l.y > -7.2134752f) ? p1.y : p2.y;
    return p * x;
}

__device__ __forceinline__ float wave_sum(float v) {
    v += __shfl_down(v, 32);
    v += __shfl_down(v, 16);
    v += __shfl_down(v, 8);
    v += __shfl_down(v, 4);
    v += __shfl_down(v, 2);
    v += __shfl_down(v, 1);
    return v;
}

// Accumulate samples [s_begin, s_end) for batch-row b (and b+256); leaves
// block-reduced partials {sum0,sq0,sum1,sq1} per k in s_fin[64].
// s_mu/s_sv hold log2e-scaled mean and log2e*sqrt(2*var): softmax in log2
// domain, NO max-subtract (|x| <= ~15 so exp2 is overflow-safe).
__device__ __forceinline__ void sg_accumulate(const float* __restrict__ mean,
                                              const float* __restrict__ var,
                                              int b, int s_begin, int s_end,
                                              float (*s_mu)[16], float (*s_sv)[16],
                                              float* s_red, float* s_fin) {
    const int tid = threadIdx.x;

    if (tid < 32) {
        int h = tid >> 4, k = tid & 15;
        int bg = b + 256 * h;
        s_mu[h][k] = LOG2E * mean[bg * 16 + k];
        s_sv[h][k] = (LOG2E * 1.41421356237309515f) * sqrtf(var[bg * 16 + k]);
    }
    __syncthreads();

    f32x2 accs0[8], accq0[8], accs1[8], accq1[8];
#pragma unroll
    for (int kp = 0; kp < 8; kp++) {
        accs0[kp] = (f32x2){0.f, 0.f}; accq0[kp] = (f32x2){0.f, 0.f};
        accs1[kp] = (f32x2){0.f, 0.f}; accq1[kp] = (f32x2){0.f, 0.f};
    }

    const uint32_t base_bk = (uint32_t)(b * 16) * 10000u;

    for (int s = s_begin + tid; s < s_end; s += THREADS) {
        f32x2 e0[8], e1[8];
#pragma unroll
        for (int kp = 0; kp < 8; kp++) {
            uint32_t ia = base_bk + (uint32_t)(kp * 20000) + (uint32_t)s;
            uint32_t ib = ia + 10000u;
            uint32_t a0, a1, b0, b1;
            tf2x32(ia, ia + HALF_N, a0, a1);
            tf2x32(ib, ib + HALF_N, b0, b1);
            f32x2 z0 = erfinv2(u2_from_bits(a0, b0));  // batch b,     k pair
            f32x2 z1 = erfinv2(u2_from_bits(a1, b1));  // batch b+256, k pair
            f32x2 mu0 = *(const f32x2*)&s_mu[0][2 * kp];
            f32x2 sv0 = *(const f32x2*)&s_sv[0][2 * kp];
            f32x2 mu1 = *(const f32x2*)&s_mu[1][2 * kp];
            f32x2 sv1 = *(const f32x2*)&s_sv[1][2 * kp];
            e0[kp] = __builtin_elementwise_fma(z0, sv0, mu0);
            e1[kp] = __builtin_elementwise_fma(z1, sv1, mu1);
        }
        f32x2 sm0 = {0.f, 0.f}, sm1 = {0.f, 0.f};
#pragma unroll
        for (int kp = 0; kp < 8; kp++) {
            f32x2 t0, t1;
            t0.x = __builtin_amdgcn_exp2f(e0[kp].x);
            t0.y = __builtin_amdgcn_exp2f(e0[kp].y);
            t1.x = __builtin_amdgcn_exp2f(e1[kp].x);
            t1.y = __builtin_amdgcn_exp2f(e1[kp].y);
            e0[kp] = t0; sm0 += t0;
            e1[kp] = t1; sm1 += t1;
        }
        float inv0 = __builtin_amdgcn_rcpf(sm0.x + sm0.y);
        float inv1 = __builtin_amdgcn_rcpf(sm1.x + sm1.y);
        f32x2 iv0 = {inv0, inv0}, iv1 = {inv1, inv1};
#pragma unroll
        for (int kp = 0; kp < 8; kp++) {
            f32x2 p0 = e0[kp] * iv0;
            f32x2 p1 = e1[kp] * iv1;
            accs0[kp] += p0;
            accq0[kp] = __builtin_elementwise_fma(p0, p0, accq0[kp]);
            accs1[kp] += p1;
            accq1[kp] = __builtin_elementwise_fma(p1, p1, accq1[kp]);
        }
    }

    const int lane = tid & 63, wave = tid >> 6;
#pragma unroll
    for (int kp = 0; kp < 8; kp++) {
#define RED(val, slot) { float r_ = wave_sum(val); if (lane == 0) s_red[wave * 64 + (slot)] = r_; }
        RED(accs0[kp].x, (2 * kp) * 4 + 0)
        RED(accq0[kp].x, (2 * kp) * 4 + 1)
        RED(accs1[kp].x, (2 * kp) * 4 + 2)
        RED(accq1[kp].x, (2 * kp) * 4 + 3)
        RED(accs0[kp].y, (2 * kp + 1) * 4 + 0)
        RED(accq0[kp].y, (2 * kp + 1) * 4 + 1)
        RED(accs1[kp].y, (2 * kp + 1) * 4 + 2)
        RED(accq1[kp].y, (2 * kp + 1) * 4 + 3)
#undef RED
    }
    __syncthreads();

    if (tid < 64) {
        float t = 0.f;
#pragma unroll
        for (int w = 0; w < 8; w++) t += s_red[w * 64 + tid];
        s_fin[tid] = t;
    }
    __syncthreads();
}

// ---- split path: 256*SPLIT blocks write partials to ws ----
__global__ __launch_bounds__(THREADS, 2)
void sg_partial(const float* __restrict__ mean, const float* __restrict__ var,
                float* __restrict__ ws) {
    __shared__ __attribute__((aligned(8))) float s_mu[2][16];
    __shared__ __attribute__((aligned(8))) float s_sv[2][16];
    __shared__ float s_red[8 * 64], s_fin[64];
    const int b = blockIdx.x >> 2;       // 0..255
    const int chunk = blockIdx.x & 3;    // 0..SPLIT-1
    sg_accumulate(mean, var, b, chunk * CHUNK, (chunk + 1) * CHUNK,
                  s_mu, s_sv, s_red, s_fin);
    if (threadIdx.x < 64) ws[blockIdx.x * 64 + threadIdx.x] = s_fin[threadIdx.x];
}

__global__ __launch_bounds__(256)
void sg_finalize(const float* __restrict__ ws, float* __restrict__ out) {
    int t = blockIdx.x * blockDim.x + threadIdx.x;  // 0..8191
    if (t >= 8192) return;
    int k = t & 15, h = (t >> 4) & 1, b = t >> 5;
    float sum = 0.f, sq = 0.f;
#pragma unroll
    for (int c = 0; c < SPLIT; c++) {
        const float* p = ws + ((b * SPLIT + c) * 64 + k * 4 + 2 * h);
        sum += p[0];
        sq += p[1];
    }
    float mu = sum * (1.0f / 10000.0f);
    float vr = (sq - sum * mu) * (1.0f / 9999.0f);  // unbiased
    int bg = b + 256 * h;
    out[bg * 16 + k] = mu;
    out[8192 + bg * 16 + k] = vr;
}

// ---- fallback (ws too small): single kernel, one block per b ----
__global__ __launch_bounds__(THREADS, 2)
void sg_kernel(const float* __restrict__ mean, const float* __restrict__ var,
               float* __restrict__ out) {
    __shared__ __attribute__((aligned(8))) float s_mu[2][16];
    __shared__ __attribute__((aligned(8))) float s_sv[2][16];
    __shared__ float s_red[8 * 64], s_fin[64];
    const int b = blockIdx.x;
    sg_accumulate(mean, var, b, 0, NSAMP, s_mu, s_sv, s_red, s_fin);
    const int tid = threadIdx.x;
    if (tid < 32) {
        int h = tid >> 4, k = tid & 15;
        float sum = s_fin[k * 4 + 2 * h + 0];
        float sq  = s_fin[k * 4 + 2 * h + 1];
        float mu = sum * (1.0f / 10000.0f);
        float vr = (sq - sum * mu) * (1.0f / 9999.0f);
        int bg = b + 256 * h;
        out[bg * 16 + k] = mu;
        out[8192 + bg * 16 + k] = vr;
    }
}

extern "C" void kernel_launch(void* const* d_in, const int* in_sizes, int n_in,
                              void* d_out, int out_size, void* d_ws, size_t ws_size,
                              hipStream_t stream) {
    const float* mean = (const float*)d_in[0];
    const float* var  = (const float*)d_in[1];
    float* out = (float*)d_out;
    if (ws_size >= WS_NEEDED) {
        float* ws = (float*)d_ws;
        sg_partial<<<256 * SPLIT, THREADS, 0, stream>>>(mean, var, ws);
        sg_finalize<<<32, 256, 0, stream>>>(ws, out);
    } else {
        sg_kernel<<<256, THREADS, 0, stream>>>(mean, var, out);
    }
}

// Round 5
// 155.631 us; speedup vs baseline: 1.2802x; 1.1909x over previous
//
#include <hip/hip_runtime.h>
#include <cstdint>
#include <math.h>

// SoftmaxGaussian: out_mean/out_var over 10000 MC softmax samples with
// JAX threefry2x32-exact random draw (key(42), shape (512,16,10000)).
//
// Layout facts:
//   N = 512*16*10000 = 81,920,000 ; half = 40,960,000 = 256*16*10000
//   flat j=(b*16+k)*10000+s ; threefry block i in [0,half):
//     counters (i, i+half), key (0,42) -> (z[j=i], z[j=i+half])
//   => block i yields samples for (b,k,s) AND (b+256,k,s).
//
// R5: R4 was latency/parallelism-bound (VALUBusy 60%, occupancy pinned at
// 23% regardless of grid). 512-thread workgroups pack poorly; switch to
// 256-thread blocks (grid still 1024 = 4 blocks/CU x 4 waves = 16 waves/CU,
// 2x R4's effective residency). launch_bounds(256,4) caps VGPR at 128 —
// current use 104, so no spill risk (R2 lesson). Numerics bit-identical
// to R4: threefry + packed Giles erfinv + log2-domain softmax, no max-sub.

typedef float f32x2 __attribute__((ext_vector_type(2)));

#define NSAMP 10000
#define HALF_N 40960000u
#define THREADS 256
#define WAVES (THREADS / 64)
#define SPLIT 4
#define CHUNK (NSAMP / SPLIT)  // 2500
#define WS_NEEDED (256 * SPLIT * 64 * sizeof(float))  // 262144 B

#define LOG2E 1.44269504088896340736f
#define NLN2 -0.69314718055994530942f
#define SQRT_LN2 0.83255461115769775635f

__device__ __forceinline__ uint32_t rotl32(uint32_t x, int r) {
    return (x << r) | (x >> (32 - r));  // v_alignbit_b32
}

// JAX threefry2x32, key = (0, 42)
__device__ __forceinline__ void tf2x32(uint32_t x0, uint32_t x1,
                                       uint32_t& o0, uint32_t& o1) {
    const uint32_t ks1 = 42u;
    const uint32_t ks2 = 0x1BD11BDAu ^ 42u;
    x1 += ks1;
#define TF_R(r) { x0 += x1; x1 = rotl32(x1, r); x1 ^= x0; }
    TF_R(13) TF_R(15) TF_R(26) TF_R(6)   x0 += ks1; x1 += ks2 + 1u;
    TF_R(17) TF_R(29) TF_R(16) TF_R(24)  x0 += ks2; x1 += 2u;
    TF_R(13) TF_R(15) TF_R(26) TF_R(6)                x1 += ks1 + 3u;
    TF_R(17) TF_R(29) TF_R(16) TF_R(24)  x0 += ks1; x1 += ks2 + 4u;
    TF_R(13) TF_R(15) TF_R(26) TF_R(6)   x0 += ks2; x1 += 5u;
#undef TF_R
    o0 = x0;
    o1 = x1;
}

// JAX uniform(lo=nextafter(-1,0), hi=1), packed pair.
// u = (f-1)*2 + lo; f-1 exact (Sterbenz), fma = one rounding (matches JAX).
__device__ __forceinline__ f32x2 u2_from_bits(uint32_t ba, uint32_t bb) {
    f32x2 f;
    f.x = __uint_as_float((ba >> 9) | 0x3F800000u);
    f.y = __uint_as_float((bb >> 9) | 0x3F800000u);
    f = f - (f32x2){1.0f, 1.0f};
    return __builtin_elementwise_fma(f, (f32x2){2.0f, 2.0f},
                                     (f32x2){-0.99999994f, -0.99999994f});
}

// XLA's ErfInv f32 (Giles 2012), branchless both-path, packed pair.
// l = log2(1-x^2) <= 0 ; w = -ln2*l ; main path w<5 <=> l > -5/ln2.
__device__ __forceinline__ f32x2 erfinv2(f32x2 x) {
    f32x2 t = __builtin_elementwise_fma(-x, x, (f32x2){1.0f, 1.0f});
    f32x2 l;
    l.x = __builtin_amdgcn_logf(t.x);
    l.y = __builtin_amdgcn_logf(t.y);
    f32x2 wm = __builtin_elementwise_fma((f32x2){NLN2, NLN2}, l,
                                         (f32x2){-2.5f, -2.5f});
#define P9(P, W, C) P = __builtin_elementwise_fma(P, W, (f32x2){C, C});
    f32x2 p1 = {2.81022636e-08f, 2.81022636e-08f};
    P9(p1, wm, 3.43273939e-07f)
    P9(p1, wm, -3.5233877e-06f)
    P9(p1, wm, -4.39150654e-06f)
    P9(p1, wm, 0.00021858087f)
    P9(p1, wm, -0.00125372503f)
    P9(p1, wm, -0.00417768164f)
    P9(p1, wm, 0.246640727f)
    P9(p1, wm, 1.50140941f)
    f32x2 sq;
    sq.x = __builtin_amdgcn_sqrtf(-l.x);   // sqrt(w2), neg folds to src-mod
    sq.y = __builtin_amdgcn_sqrtf(-l.y);
    f32x2 wt = __builtin_elementwise_fma((f32x2){SQRT_LN2, SQRT_LN2}, sq,
                                         (f32x2){-3.0f, -3.0f});
    f32x2 p2 = {-0.000200214257f, -0.000200214257f};
    P9(p2, wt, 0.000100950558f)
    P9(p2, wt, 0.00134934322f)
    P9(p2, wt, -0.00367342844f)
    P9(p2, wt, 0.00573950773f)
    P9(p2, wt, -0.0076224613f)
    P9(p2, wt, 0.00943887047f)
    P9(p2, wt, 1.00167406f)
    P9(p2, wt, 2.83297682f)
#undef P9
    f32x2 p;
    p.x = (l.x > -7.2134752f) ? p1.x : p2.x;  // -5/ln2
    p.y = (l.y > -7.2134752f) ? p1.y : p2.y;
    return p * x;
}

__device__ __forceinline__ float wave_sum(float v) {
    v += __shfl_down(v, 32);
    v += __shfl_down(v, 16);
    v += __shfl_down(v, 8);
    v += __shfl_down(v, 4);
    v += __shfl_down(v, 2);
    v += __shfl_down(v, 1);
    return v;
}

// Accumulate samples [s_begin, s_end) for batch-row b (and b+256); leaves
// block-reduced partials {sum0,sq0,sum1,sq1} per k in s_fin[64].
// s_mu/s_sv hold log2e-scaled mean and log2e*sqrt(2*var): softmax in log2
// domain, NO max-subtract (|x| <= ~15 so exp2 is overflow-safe).
__device__ __forceinline__ void sg_accumulate(const float* __restrict__ mean,
                                              const float* __restrict__ var,
                                              int b, int s_begin, int s_end,
                                              float (*s_mu)[16], float (*s_sv)[16],
                                              float* s_red, float* s_fin) {
    const int tid = threadIdx.x;

    if (tid < 32) {
        int h = tid >> 4, k = tid & 15;
        int bg = b + 256 * h;
        s_mu[h][k] = LOG2E * mean[bg * 16 + k];
        s_sv[h][k] = (LOG2E * 1.41421356237309515f) * sqrtf(var[bg * 16 + k]);
    }
    __syncthreads();

    f32x2 accs0[8], accq0[8], accs1[8], accq1[8];
#pragma unroll
    for (int kp = 0; kp < 8; kp++) {
        accs0[kp] = (f32x2){0.f, 0.f}; accq0[kp] = (f32x2){0.f, 0.f};
        accs1[kp] = (f32x2){0.f, 0.f}; accq1[kp] = (f32x2){0.f, 0.f};
    }

    const uint32_t base_bk = (uint32_t)(b * 16) * 10000u;

    for (int s = s_begin + tid; s < s_end; s += THREADS) {
        f32x2 e0[8], e1[8];
#pragma unroll
        for (int kp = 0; kp < 8; kp++) {
            uint32_t ia = base_bk + (uint32_t)(kp * 20000) + (uint32_t)s;
            uint32_t ib = ia + 10000u;
            uint32_t a0, a1, b0, b1;
            tf2x32(ia, ia + HALF_N, a0, a1);
            tf2x32(ib, ib + HALF_N, b0, b1);
            f32x2 z0 = erfinv2(u2_from_bits(a0, b0));  // batch b,     k pair
            f32x2 z1 = erfinv2(u2_from_bits(a1, b1));  // batch b+256, k pair
            f32x2 mu0 = *(const f32x2*)&s_mu[0][2 * kp];
            f32x2 sv0 = *(const f32x2*)&s_sv[0][2 * kp];
            f32x2 mu1 = *(const f32x2*)&s_mu[1][2 * kp];
            f32x2 sv1 = *(const f32x2*)&s_sv[1][2 * kp];
            e0[kp] = __builtin_elementwise_fma(z0, sv0, mu0);
            e1[kp] = __builtin_elementwise_fma(z1, sv1, mu1);
        }
        f32x2 sm0 = {0.f, 0.f}, sm1 = {0.f, 0.f};
#pragma unroll
        for (int kp = 0; kp < 8; kp++) {
            f32x2 t0, t1;
            t0.x = __builtin_amdgcn_exp2f(e0[kp].x);
            t0.y = __builtin_amdgcn_exp2f(e0[kp].y);
            t1.x = __builtin_amdgcn_exp2f(e1[kp].x);
            t1.y = __builtin_amdgcn_exp2f(e1[kp].y);
            e0[kp] = t0; sm0 += t0;
            e1[kp] = t1; sm1 += t1;
        }
        float inv0 = __builtin_amdgcn_rcpf(sm0.x + sm0.y);
        float inv1 = __builtin_amdgcn_rcpf(sm1.x + sm1.y);
        f32x2 iv0 = {inv0, inv0}, iv1 = {inv1, inv1};
#pragma unroll
        for (int kp = 0; kp < 8; kp++) {
            f32x2 p0 = e0[kp] * iv0;
            f32x2 p1 = e1[kp] * iv1;
            accs0[kp] += p0;
            accq0[kp] = __builtin_elementwise_fma(p0, p0, accq0[kp]);
            accs1[kp] += p1;
            accq1[kp] = __builtin_elementwise_fma(p1, p1, accq1[kp]);
        }
    }

    const int lane = tid & 63, wave = tid >> 6;
#pragma unroll
    for (int kp = 0; kp < 8; kp++) {
#define RED(val, slot) { float r_ = wave_sum(val); if (lane == 0) s_red[wave * 64 + (slot)] = r_; }
        RED(accs0[kp].x, (2 * kp) * 4 + 0)
        RED(accq0[kp].x, (2 * kp) * 4 + 1)
        RED(accs1[kp].x, (2 * kp) * 4 + 2)
        RED(accq1[kp].x, (2 * kp) * 4 + 3)
        RED(accs0[kp].y, (2 * kp + 1) * 4 + 0)
        RED(accq0[kp].y, (2 * kp + 1) * 4 + 1)
        RED(accs1[kp].y, (2 * kp + 1) * 4 + 2)
        RED(accq1[kp].y, (2 * kp + 1) * 4 + 3)
#undef RED
    }
    __syncthreads();

    if (tid < 64) {
        float t = 0.f;
#pragma unroll
        for (int w = 0; w < WAVES; w++) t += s_red[w * 64 + tid];
        s_fin[tid] = t;
    }
    __syncthreads();
}

// ---- split path: 256*SPLIT blocks write partials to ws ----
__global__ __launch_bounds__(THREADS, 4)
void sg_partial(const float* __restrict__ mean, const float* __restrict__ var,
                float* __restrict__ ws) {
    __shared__ __attribute__((aligned(8))) float s_mu[2][16];
    __shared__ __attribute__((aligned(8))) float s_sv[2][16];
    __shared__ float s_red[WAVES * 64], s_fin[64];
    const int b = blockIdx.x >> 2;       // 0..255
    const int chunk = blockIdx.x & 3;    // 0..SPLIT-1
    sg_accumulate(mean, var, b, chunk * CHUNK, (chunk + 1) * CHUNK,
                  s_mu, s_sv, s_red, s_fin);
    if (threadIdx.x < 64) ws[blockIdx.x * 64 + threadIdx.x] = s_fin[threadIdx.x];
}

__global__ __launch_bounds__(256)
void sg_finalize(const float* __restrict__ ws, float* __restrict__ out) {
    int t = blockIdx.x * blockDim.x + threadIdx.x;  // 0..8191
    if (t >= 8192) return;
    int k = t & 15, h = (t >> 4) & 1, b = t >> 5;
    float sum = 0.f, sq = 0.f;
#pragma unroll
    for (int c = 0; c < SPLIT; c++) {
        const float* p = ws + ((b * SPLIT + c) * 64 + k * 4 + 2 * h);
        sum += p[0];
        sq += p[1];
    }
    float mu = sum * (1.0f / 10000.0f);
    float vr = (sq - sum * mu) * (1.0f / 9999.0f);  // unbiased
    int bg = b + 256 * h;
    out[bg * 16 + k] = mu;
    out[8192 + bg * 16 + k] = vr;
}

// ---- fallback (ws too small): single kernel, one block per b ----
__global__ __launch_bounds__(THREADS, 4)
void sg_kernel(const float* __restrict__ mean, const float* __restrict__ var,
               float* __restrict__ out) {
    __shared__ __attribute__((aligned(8))) float s_mu[2][16];
    __shared__ __attribute__((aligned(8))) float s_sv[2][16];
    __shared__ float s_red[WAVES * 64], s_fin[64];
    const int b = blockIdx.x;
    sg_accumulate(mean, var, b, 0, NSAMP, s_mu, s_sv, s_red, s_fin);
    const int tid = threadIdx.x;
    if (tid < 32) {
        int h = tid >> 4, k = tid & 15;
        float sum = s_fin[k * 4 + 2 * h + 0];
        float sq  = s_fin[k * 4 + 2 * h + 1];
        float mu = sum * (1.0f / 10000.0f);
        float vr = (sq - sum * mu) * (1.0f / 9999.0f);
        int bg = b + 256 * h;
        out[bg * 16 + k] = mu;
        out[8192 + bg * 16 + k] = vr;
    }
}

extern "C" void kernel_launch(void* const* d_in, const int* in_sizes, int n_in,
                              void* d_out, int out_size, void* d_ws, size_t ws_size,
                              hipStream_t stream) {
    const float* mean = (const float*)d_in[0];
    const float* var  = (const float*)d_in[1];
    float* out = (float*)d_out;
    if (ws_size >= WS_NEEDED) {
        float* ws = (float*)d_ws;
        sg_partial<<<256 * SPLIT, THREADS, 0, stream>>>(mean, var, ws);
        sg_finalize<<<32, 256, 0, stream>>>(ws, out);
    } else {
        sg_kernel<<<256, THREADS, 0, stream>>>(mean, var, out);
    }
}

// Round 6
// 145.682 us; speedup vs baseline: 1.3676x; 1.0683x over previous
//
#include <hip/hip_runtime.h>
#include <cstdint>
#include <math.h>

// SoftmaxGaussian: out_mean/out_var over 10000 MC softmax samples with
// JAX threefry2x32-exact random draw (key(42), shape (512,16,10000)).
//
// Layout facts:
//   N = 512*16*10000 = 81,920,000 ; half = 40,960,000 = 256*16*10000
//   flat j=(b*16+k)*10000+s ; threefry block i in [0,half):
//     counters (i, i+half), key (0,42) -> (z[j=i], z[j=i+half])
//   => block i yields samples for (b,k,s) AND (b+256,k,s).
//
// R6: R5's launch_bounds(256,4) AGAIN forced a 64-VGPR cap -> spills
// (98+65 MB scratch traffic), yet still won via 16 waves/CU residency.
// Empirical rule (R2/R4/R5): 2nd arg 4 => 64-VGPR cap+spill; 2nd arg 2 =>
// natural ~104 VGPR, no spill. So: 256-thread blocks + launch_bounds(256,2).
// 104 VGPR still permits 4 waves/SIMD (halving at 64/128/256) => residency
// unchanged, spill traffic deleted. Numerics bit-identical to R4/R5.

typedef float f32x2 __attribute__((ext_vector_type(2)));

#define NSAMP 10000
#define HALF_N 40960000u
#define THREADS 256
#define WAVES (THREADS / 64)
#define SPLIT 4
#define CHUNK (NSAMP / SPLIT)  // 2500
#define WS_NEEDED (256 * SPLIT * 64 * sizeof(float))  // 262144 B

#define LOG2E 1.44269504088896340736f
#define NLN2 -0.69314718055994530942f
#define SQRT_LN2 0.83255461115769775635f

__device__ __forceinline__ uint32_t rotl32(uint32_t x, int r) {
    return (x << r) | (x >> (32 - r));  // v_alignbit_b32
}

// JAX threefry2x32, key = (0, 42)
__device__ __forceinline__ void tf2x32(uint32_t x0, uint32_t x1,
                                       uint32_t& o0, uint32_t& o1) {
    const uint32_t ks1 = 42u;
    const uint32_t ks2 = 0x1BD11BDAu ^ 42u;
    x1 += ks1;
#define TF_R(r) { x0 += x1; x1 = rotl32(x1, r); x1 ^= x0; }
    TF_R(13) TF_R(15) TF_R(26) TF_R(6)   x0 += ks1; x1 += ks2 + 1u;
    TF_R(17) TF_R(29) TF_R(16) TF_R(24)  x0 += ks2; x1 += 2u;
    TF_R(13) TF_R(15) TF_R(26) TF_R(6)                x1 += ks1 + 3u;
    TF_R(17) TF_R(29) TF_R(16) TF_R(24)  x0 += ks1; x1 += ks2 + 4u;
    TF_R(13) TF_R(15) TF_R(26) TF_R(6)   x0 += ks2; x1 += 5u;
#undef TF_R
    o0 = x0;
    o1 = x1;
}

// JAX uniform(lo=nextafter(-1,0), hi=1), packed pair.
// u = (f-1)*2 + lo; f-1 exact (Sterbenz), fma = one rounding (matches JAX).
__device__ __forceinline__ f32x2 u2_from_bits(uint32_t ba, uint32_t bb) {
    f32x2 f;
    f.x = __uint_as_float((ba >> 9) | 0x3F800000u);
    f.y = __uint_as_float((bb >> 9) | 0x3F800000u);
    f = f - (f32x2){1.0f, 1.0f};
    return __builtin_elementwise_fma(f, (f32x2){2.0f, 2.0f},
                                     (f32x2){-0.99999994f, -0.99999994f});
}

// XLA's ErfInv f32 (Giles 2012), branchless both-path, packed pair.
// l = log2(1-x^2) <= 0 ; w = -ln2*l ; main path w<5 <=> l > -5/ln2.
__device__ __forceinline__ f32x2 erfinv2(f32x2 x) {
    f32x2 t = __builtin_elementwise_fma(-x, x, (f32x2){1.0f, 1.0f});
    f32x2 l;
    l.x = __builtin_amdgcn_logf(t.x);
    l.y = __builtin_amdgcn_logf(t.y);
    f32x2 wm = __builtin_elementwise_fma((f32x2){NLN2, NLN2}, l,
                                         (f32x2){-2.5f, -2.5f});
#define P9(P, W, C) P = __builtin_elementwise_fma(P, W, (f32x2){C, C});
    f32x2 p1 = {2.81022636e-08f, 2.81022636e-08f};
    P9(p1, wm, 3.43273939e-07f)
    P9(p1, wm, -3.5233877e-06f)
    P9(p1, wm, -4.39150654e-06f)
    P9(p1, wm, 0.00021858087f)
    P9(p1, wm, -0.00125372503f)
    P9(p1, wm, -0.00417768164f)
    P9(p1, wm, 0.246640727f)
    P9(p1, wm, 1.50140941f)
    f32x2 sq;
    sq.x = __builtin_amdgcn_sqrtf(-l.x);   // sqrt(w2), neg folds to src-mod
    sq.y = __builtin_amdgcn_sqrtf(-l.y);
    f32x2 wt = __builtin_elementwise_fma((f32x2){SQRT_LN2, SQRT_LN2}, sq,
                                         (f32x2){-3.0f, -3.0f});
    f32x2 p2 = {-0.000200214257f, -0.000200214257f};
    P9(p2, wt, 0.000100950558f)
    P9(p2, wt, 0.00134934322f)
    P9(p2, wt, -0.00367342844f)
    P9(p2, wt, 0.00573950773f)
    P9(p2, wt, -0.0076224613f)
    P9(p2, wt, 0.00943887047f)
    P9(p2, wt, 1.00167406f)
    P9(p2, wt, 2.83297682f)
#undef P9
    f32x2 p;
    p.x = (l.x > -7.2134752f) ? p1.x : p2.x;  // -5/ln2
    p.y = (l.y > -7.2134752f) ? p1.y : p2.y;
    return p * x;
}

__device__ __forceinline__ float wave_sum(float v) {
    v += __shfl_down(v, 32);
    v += __shfl_down(v, 16);
    v += __shfl_down(v, 8);
    v += __shfl_down(v, 4);
    v += __shfl_down(v, 2);
    v += __shfl_down(v, 1);
    return v;
}

// Accumulate samples [s_begin, s_end) for batch-row b (and b+256); leaves
// block-reduced partials {sum0,sq0,sum1,sq1} per k in s_fin[64].
// s_mu/s_sv hold log2e-scaled mean and log2e*sqrt(2*var): softmax in log2
// domain, NO max-subtract (|x| <= ~15 so exp2 is overflow-safe).
__device__ __forceinline__ void sg_accumulate(const float* __restrict__ mean,
                                              const float* __restrict__ var,
                                              int b, int s_begin, int s_end,
                                              float (*s_mu)[16], float (*s_sv)[16],
                                              float* s_red, float* s_fin) {
    const int tid = threadIdx.x;

    if (tid < 32) {
        int h = tid >> 4, k = tid & 15;
        int bg = b + 256 * h;
        s_mu[h][k] = LOG2E * mean[bg * 16 + k];
        s_sv[h][k] = (LOG2E * 1.41421356237309515f) * sqrtf(var[bg * 16 + k]);
    }
    __syncthreads();

    f32x2 accs0[8], accq0[8], accs1[8], accq1[8];
#pragma unroll
    for (int kp = 0; kp < 8; kp++) {
        accs0[kp] = (f32x2){0.f, 0.f}; accq0[kp] = (f32x2){0.f, 0.f};
        accs1[kp] = (f32x2){0.f, 0.f}; accq1[kp] = (f32x2){0.f, 0.f};
    }

    const uint32_t base_bk = (uint32_t)(b * 16) * 10000u;

    for (int s = s_begin + tid; s < s_end; s += THREADS) {
        f32x2 e0[8], e1[8];
#pragma unroll
        for (int kp = 0; kp < 8; kp++) {
            uint32_t ia = base_bk + (uint32_t)(kp * 20000) + (uint32_t)s;
            uint32_t ib = ia + 10000u;
            uint32_t a0, a1, b0, b1;
            tf2x32(ia, ia + HALF_N, a0, a1);
            tf2x32(ib, ib + HALF_N, b0, b1);
            f32x2 z0 = erfinv2(u2_from_bits(a0, b0));  // batch b,     k pair
            f32x2 z1 = erfinv2(u2_from_bits(a1, b1));  // batch b+256, k pair
            f32x2 mu0 = *(const f32x2*)&s_mu[0][2 * kp];
            f32x2 sv0 = *(const f32x2*)&s_sv[0][2 * kp];
            f32x2 mu1 = *(const f32x2*)&s_mu[1][2 * kp];
            f32x2 sv1 = *(const f32x2*)&s_sv[1][2 * kp];
            e0[kp] = __builtin_elementwise_fma(z0, sv0, mu0);
            e1[kp] = __builtin_elementwise_fma(z1, sv1, mu1);
        }
        f32x2 sm0 = {0.f, 0.f}, sm1 = {0.f, 0.f};
#pragma unroll
        for (int kp = 0; kp < 8; kp++) {
            f32x2 t0, t1;
            t0.x = __builtin_amdgcn_exp2f(e0[kp].x);
            t0.y = __builtin_amdgcn_exp2f(e0[kp].y);
            t1.x = __builtin_amdgcn_exp2f(e1[kp].x);
            t1.y = __builtin_amdgcn_exp2f(e1[kp].y);
            e0[kp] = t0; sm0 += t0;
            e1[kp] = t1; sm1 += t1;
        }
        float inv0 = __builtin_amdgcn_rcpf(sm0.x + sm0.y);
        float inv1 = __builtin_amdgcn_rcpf(sm1.x + sm1.y);
        f32x2 iv0 = {inv0, inv0}, iv1 = {inv1, inv1};
#pragma unroll
        for (int kp = 0; kp < 8; kp++) {
            f32x2 p0 = e0[kp] * iv0;
            f32x2 p1 = e1[kp] * iv1;
            accs0[kp] += p0;
            accq0[kp] = __builtin_elementwise_fma(p0, p0, accq0[kp]);
            accs1[kp] += p1;
            accq1[kp] = __builtin_elementwise_fma(p1, p1, accq1[kp]);
        }
    }

    const int lane = tid & 63, wave = tid >> 6;
#pragma unroll
    for (int kp = 0; kp < 8; kp++) {
#define RED(val, slot) { float r_ = wave_sum(val); if (lane == 0) s_red[wave * 64 + (slot)] = r_; }
        RED(accs0[kp].x, (2 * kp) * 4 + 0)
        RED(accq0[kp].x, (2 * kp) * 4 + 1)
        RED(accs1[kp].x, (2 * kp) * 4 + 2)
        RED(accq1[kp].x, (2 * kp) * 4 + 3)
        RED(accs0[kp].y, (2 * kp + 1) * 4 + 0)
        RED(accq0[kp].y, (2 * kp + 1) * 4 + 1)
        RED(accs1[kp].y, (2 * kp + 1) * 4 + 2)
        RED(accq1[kp].y, (2 * kp + 1) * 4 + 3)
#undef RED
    }
    __syncthreads();

    if (tid < 64) {
        float t = 0.f;
#pragma unroll
        for (int w = 0; w < WAVES; w++) t += s_red[w * 64 + tid];
        s_fin[tid] = t;
    }
    __syncthreads();
}

// ---- split path: 256*SPLIT blocks write partials to ws ----
__global__ __launch_bounds__(THREADS, 2)
void sg_partial(const float* __restrict__ mean, const float* __restrict__ var,
                float* __restrict__ ws) {
    __shared__ __attribute__((aligned(8))) float s_mu[2][16];
    __shared__ __attribute__((aligned(8))) float s_sv[2][16];
    __shared__ float s_red[WAVES * 64], s_fin[64];
    const int b = blockIdx.x >> 2;       // 0..255
    const int chunk = blockIdx.x & 3;    // 0..SPLIT-1
    sg_accumulate(mean, var, b, chunk * CHUNK, (chunk + 1) * CHUNK,
                  s_mu, s_sv, s_red, s_fin);
    if (threadIdx.x < 64) ws[blockIdx.x * 64 + threadIdx.x] = s_fin[threadIdx.x];
}

__global__ __launch_bounds__(256)
void sg_finalize(const float* __restrict__ ws, float* __restrict__ out) {
    int t = blockIdx.x * blockDim.x + threadIdx.x;  // 0..8191
    if (t >= 8192) return;
    int k = t & 15, h = (t >> 4) & 1, b = t >> 5;
    float sum = 0.f, sq = 0.f;
#pragma unroll
    for (int c = 0; c < SPLIT; c++) {
        const float* p = ws + ((b * SPLIT + c) * 64 + k * 4 + 2 * h);
        sum += p[0];
        sq += p[1];
    }
    float mu = sum * (1.0f / 10000.0f);
    float vr = (sq - sum * mu) * (1.0f / 9999.0f);  // unbiased
    int bg = b + 256 * h;
    out[bg * 16 + k] = mu;
    out[8192 + bg * 16 + k] = vr;
}

// ---- fallback (ws too small): single kernel, one block per b ----
__global__ __launch_bounds__(THREADS, 2)
void sg_kernel(const float* __restrict__ mean, const float* __restrict__ var,
               float* __restrict__ out) {
    __shared__ __attribute__((aligned(8))) float s_mu[2][16];
    __shared__ __attribute__((aligned(8))) float s_sv[2][16];
    __shared__ float s_red[WAVES * 64], s_fin[64];
    const int b = blockIdx.x;
    sg_accumulate(mean, var, b, 0, NSAMP, s_mu, s_sv, s_red, s_fin);
    const int tid = threadIdx.x;
    if (tid < 32) {
        int h = tid >> 4, k = tid & 15;
        float sum = s_fin[k * 4 + 2 * h + 0];
        float sq  = s_fin[k * 4 + 2 * h + 1];
        float mu = sum * (1.0f / 10000.0f);
        float vr = (sq - sum * mu) * (1.0f / 9999.0f);
        int bg = b + 256 * h;
        out[bg * 16 + k] = mu;
        out[8192 + bg * 16 + k] = vr;
    }
}

extern "C" void kernel_launch(void* const* d_in, const int* in_sizes, int n_in,
                              void* d_out, int out_size, void* d_ws, size_t ws_size,
                              hipStream_t stream) {
    const float* mean = (const float*)d_in[0];
    const float* var  = (const float*)d_in[1];
    float* out = (float*)d_out;
    if (ws_size >= WS_NEEDED) {
        float* ws = (float*)d_ws;
        sg_partial<<<256 * SPLIT, THREADS, 0, stream>>>(mean, var, ws);
        sg_finalize<<<32, 256, 0, stream>>>(ws, out);
    } else {
        sg_kernel<<<256, THREADS, 0, stream>>>(mean, var, out);
    }
}